// Round 5
// baseline (5655.854 us; speedup 1.0000x reference)
//
#include <hip/hip_runtime.h>
#include <stdint.h>
#include <stddef.h>

// ---------------------------------------------------------------------------
// SNN policy forward, MI355X. B=2048, F=256, H=1024, O=256, T=64.
// 256 blocks x 512 threads (8 waves = 2/SIMD). Block = 128 rows x 64 h.
// Wave (nj,mi,kq): tile 64m(2Mt) x 32n(nj), K-chunks of parity kq (12 of 24).
// Partner waves (kq=0/1) sum main-GEMM partials via LDS (phase A); readout
// partials exchanged in phase B (same 36KB stage region — 32KB each; the
// round-4 bug was putting phase B in the 25KB bits region -> LDS OOB).
// v_mfma_f32_32x32x16_f16, A = spikes {0,1} exact, B = f32 weights hi+lo f16.
// ---------------------------------------------------------------------------

typedef _Float16 v8h  __attribute__((ext_vector_type(8)));
typedef float    v16f __attribute__((ext_vector_type(16)));

// workspace layout (bytes)
#define OFF_WSTM  0ull                 // main W tiles [hb16][c24][p2][64][72] f16 = 7,077,888
#define OFF_WSTO  7077888ull           // w_out tiles  [hb16][c16][p2][32][64] f16 = 2,097,152
#define OFF_BITS  9175040ull           // u32 ring [64][2048][48] = 25,165,824
#define OFF_CTR   34340864ull          // u32 [16][64] group barrier counters

#define SLOT_U32  (2048*48)

__device__ __forceinline__ float frn_add(float a, float b){ return __fadd_rn(a,b); }
__device__ __forceinline__ float frn_sub(float a, float b){ return __fsub_rn(a,b); }
__device__ __forceinline__ float frn_mul(float a, float b){ return __fmul_rn(a,b); }

// ---------------------------------------------------------------------------
// prep: tile/convert weights to hi/lo f16, zero bits slot 0 + counters
// ---------------------------------------------------------------------------
__global__ void k_prep(const float* __restrict__ w_in, const float* __restrict__ w_rec,
                       const float* __restrict__ w_out, uint8_t* __restrict__ ws)
{
    const long long stride = (long long)gridDim.x * blockDim.x;
    const long long id = (long long)blockIdx.x * blockDim.x + threadIdx.x;

    _Float16* wm = (_Float16*)(ws + OFF_WSTM);
    for (long long i = id; i < 16LL*24*2*64*72; i += stride) {
        int kk = (int)(i % 72); long long t2 = i / 72;
        int hrow = (int)(t2 % 64); t2 /= 64;
        int p = (int)(t2 % 2);  t2 /= 2;
        int c = (int)(t2 % 24); int hb = (int)(t2 / 24);
        _Float16 val = (_Float16)0.0f;
        if (kk < 64) {
            int h = hb*64 + hrow; int k = c*64 + kk;
            float wv = (k < 512) ? w_in[(size_t)h*512 + k] : w_rec[(size_t)h*1024 + (k - 512)];
            _Float16 hi = (_Float16)wv;
            val = p ? (_Float16)(wv - (float)hi) : hi;
        }
        wm[i] = val;
    }

    // w_out tiles: [(hb*16+c)*2+p][n32][k64], o = hb*16+n (n<16 real, else 0), h = c*64+k
    _Float16* wo = (_Float16*)(ws + OFF_WSTO);
    for (long long i = id; i < 16LL*16*2*32*64; i += stride) {
        int k = (int)(i % 64); long long t2 = i / 64;
        int n = (int)(t2 % 32); t2 /= 32;
        int p = (int)(t2 % 2); t2 /= 2;
        int c = (int)(t2 % 16); int hb = (int)(t2 / 16);
        _Float16 val = (_Float16)0.0f;
        if (n < 16) {
            float wv = w_out[(size_t)(hb*16 + n)*1024 + c*64 + k];
            _Float16 hi = (_Float16)wv;
            val = p ? (_Float16)(wv - (float)hi) : hi;
        }
        wo[i] = val;
    }

    uint32_t* bz = (uint32_t*)(ws + OFF_BITS);
    for (long long i = id; i < SLOT_U32; i += stride) bz[i] = 0u;   // slot 0: z(-1)=0
    uint32_t* ctr = (uint32_t*)(ws + OFF_CTR);
    for (long long i = id; i < 16*64; i += stride) ctr[i] = 0u;
}

// ---------------------------------------------------------------------------
// main persistent kernel
// ---------------------------------------------------------------------------
__global__ __launch_bounds__(512, 2)
void k_snn(const float* __restrict__ x, uint8_t* __restrict__ ws,
           float* __restrict__ outm, const int* __restrict__ seqp)
{
    extern __shared__ uint8_t smem[];
    // [0, 36864): B stage, 2 slots x [p2][64][72] f16 (slot = chunk parity = kq)
    //             aliased end-of-step by Xm (phase A, 32KB) then Xo (phase B, 32KB)
    // [36864, 61952): bits LDS [128][49] u32 (25088 B)

    const int tid  = threadIdx.x;
    const int lane = tid & 63;
    const int wv   = tid >> 6;        // wave 0..7
    const int kq   = wv & 1;          // K parity (chunks c%2==kq)
    const int mi   = (wv >> 1) & 1;   // M half (64 rows)
    const int nj   = wv >> 2;         // N half (32 h)
    const int q    = lane >> 5;
    const int ln   = lane & 31;

    const int b  = blockIdx.x;
    const int bb = b >> 4;                                 // group / batch tile
    const int hb = ((b & 7) << 1) | ((b >> 3) & 1);        // h-slice, XCD-local pairs
    const int rowBase = bb * 128;

    int T = *seqp; if (T > 64) T = 64; if (T < 1) T = 1;

    // o-state: each wave owns rows [wv*16, wv*16+16) x 16 o-cols; 4 elems/lane
    const int colo = ln & 15, rgrp = lane >> 4;            // rgrp 0..3
    float io4[4], vo4[4], mx4[4];
#pragma unroll
    for (int i = 0; i < 4; ++i) { io4[i] = 0.f; vo4[i] = 0.f; mx4[i] = 0.f; }

    v16f zv;
#pragma unroll
    for (int k = 0; k < 16; ++k) zv[k] = 0.f;
    v16f vS = zv, iS = zv;            // owned hidden tile: rows mi*64+kq*32, cols hb*64+nj*32

    // encoder: thread -> row (tid>>2), 8 features at (tid&3)*8
    const int er  = tid >> 2;
    const int fq  = tid & 3;
    float ve[8], cc[8];
    {
        const float* xr = x + (size_t)(rowBase + er) * 256 + (hb & 7) * 32 + fq * 8;
        const float sgn = (hb < 8) ? 50.0f : -50.0f;
#pragma unroll
        for (int f = 0; f < 8; ++f) {
            cc[f] = fmaxf(frn_mul(sgn, xr[f]), 0.0f);
            ve[f] = 0.0f;
        }
    }

    uint32_t* const bitsRing = (uint32_t*)(ws + OFF_BITS);
    uint32_t* const bitsL = (uint32_t*)(smem + 36864);
    uint32_t* const ctr = (uint32_t*)(ws + OFF_CTR) + bb * 64;
    const uint4* const wstg = (const uint4*)(ws + OFF_WSTM) + (size_t)(hb * 24) * 1152;
    const _Float16* const wouts = (const _Float16*)(ws + OFF_WSTO);
    uint4* const Bs = (uint4*)smem;

    auto enc_step = [&](int dstSlot) {
        uint32_t byte = 0;
#pragma unroll
        for (int f = 0; f < 8; ++f) {
            float vv = ve[f];
            vv = frn_add(vv, frn_mul(0.1f, frn_add(frn_sub(0.0f, vv), cc[f])));
            bool zz = frn_sub(vv, 1.0f) > 0.0f;
            ve[f] = zz ? 0.0f : vv;
            byte |= zz ? (1u << f) : 0u;
        }
        uint32_t w = byte << (fq * 8);
        w |= __shfl_xor(w, 1);
        w |= __shfl_xor(w, 2);
        if (fq == 0)
            __hip_atomic_store(&bitsRing[(size_t)dstSlot * SLOT_U32 + (size_t)(rowBase + er) * 48 + hb],
                               w, __ATOMIC_RELAXED, __HIP_MEMORY_SCOPE_AGENT);
    };

    auto gbar = [&](int phase) {
        asm volatile("s_waitcnt vmcnt(0)" ::: "memory");
        __syncthreads();
        if (tid == 0) {
            __hip_atomic_fetch_add(ctr, 1u, __ATOMIC_RELAXED, __HIP_MEMORY_SCOPE_AGENT);
            const uint32_t tgt = 16u * (uint32_t)(phase + 1);
            while (__hip_atomic_load(ctr, __ATOMIC_RELAXED, __HIP_MEMORY_SCOPE_AGENT) < tgt)
                __builtin_amdgcn_s_sleep(1);
            asm volatile("" ::: "memory");
        }
        __syncthreads();
    };

    enc_step(0);   // xt(0) -> slot 0

    // staging regs: chunk pair = 2304 uint4 over 512 threads
    uint4 pf[5];
    auto pair_load = [&](int pr) {
        const uint4* g = wstg + (size_t)(pr * 2) * 1152;
        pf[0] = g[tid]; pf[1] = g[tid + 512]; pf[2] = g[tid + 1024]; pf[3] = g[tid + 1536];
        if (tid < 256) pf[4] = g[tid + 2048];
    };
    auto pair_store = [&]() {
        Bs[tid] = pf[0]; Bs[tid + 512] = pf[1]; Bs[tid + 1024] = pf[2]; Bs[tid + 1536] = pf[3];
        if (tid < 256) Bs[tid + 2048] = pf[4];
    };
    pair_load(0);

    const _Float16* const Bt = (const _Float16*)(smem + kq * 18432);

    for (int t = 0; t < T; ++t) {
        gbar(t);

        // ---- bits slot t -> LDS [128][49] (12 agent loads/thread) ----
        uint32_t bw[12];
        {
            const uint32_t* bsrc = bitsRing + (size_t)t * SLOT_U32 + (size_t)rowBase * 48;
#pragma unroll
            for (int i2 = 0; i2 < 12; ++i2)
                bw[i2] = __hip_atomic_load(bsrc + tid + i2 * 512,
                                           __ATOMIC_RELAXED, __HIP_MEMORY_SCOPE_AGENT);
        }
        pair_store();    // pair 0 (preloaded before loop / at end of prev step)
#pragma unroll
        for (int i2 = 0; i2 < 12; ++i2) {
            int idx = tid + i2 * 512;
            int r = idx / 48, wq = idx - r * 48;
            bitsL[r * 49 + wq] = bw[i2];
        }
        __syncthreads();

        v16f acc_h[2], acc_l[2], oacc[2];
        acc_h[0] = zv; acc_h[1] = zv; acc_l[0] = zv; acc_l[1] = zv;
        oacc[0] = zv; oacc[1] = zv;

        for (int j = 0; j < 12; ++j) {
            const int c = 2 * j + kq;
            if (j < 11) pair_load(j + 1);

            const bool odut = (c >= 8) && ((c >= 16) == (nj == 1));
            uint4 wof[8];
            if (odut) {
                const _Float16* wob = wouts + ((size_t)(hb * 16 + (c - 8)) * 2) * 2048;
#pragma unroll
                for (int kc = 0; kc < 4; ++kc)
#pragma unroll
                    for (int p = 0; p < 2; ++p)
                        wof[kc * 2 + p] = *(const uint4*)(wob + (size_t)p * 2048 + ln * 64 + kc * 16 + q * 8);
            }

            uint32_t wb[2];
#pragma unroll
            for (int kc = 0; kc < 4; ++kc) {
                if ((kc & 1) == 0) {
#pragma unroll
                    for (int Mt = 0; Mt < 2; ++Mt)
                        wb[Mt] = bitsL[(mi * 64 + Mt * 32 + ln) * 49 + (c * 2 + (kc >> 1))];
                }
                v8h A[2];
#pragma unroll
                for (int Mt = 0; Mt < 2; ++Mt) {
                    const uint32_t wv2 = wb[Mt];
                    const int sh = ((kc & 1) << 4) + (q << 3);
                    union { uint32_t u[4]; v8h h; } ua;
#pragma unroll
                    for (int j2 = 0; j2 < 4; ++j2) {
                        uint32_t pr = (wv2 >> (sh + 2 * j2)) & 3u;
                        uint32_t m = (pr | (pr << 15)) & 0x10001u;
                        ua.u[j2] = m * 0x3C00u;     // {0,1} spikes -> f16 pair
                    }
                    A[Mt] = ua.h;
                }
                const _Float16* brow = Bt + (size_t)(nj * 32 + ln) * 72 + kc * 16 + q * 8;
                v8h Bh = *(const v8h*)brow;
                v8h Bl = *(const v8h*)(brow + 64 * 72);
#pragma unroll
                for (int Mt = 0; Mt < 2; ++Mt) {
                    acc_h[Mt] = __builtin_amdgcn_mfma_f32_32x32x16_f16(A[Mt], Bh, acc_h[Mt], 0, 0, 0);
                    acc_l[Mt] = __builtin_amdgcn_mfma_f32_32x32x16_f16(A[Mt], Bl, acc_l[Mt], 0, 0, 0);
                }
                if (odut) {
                    union { uint4 u; v8h h; } bo0, bo1;
                    bo0.u = wof[kc * 2 + 0]; bo1.u = wof[kc * 2 + 1];
#pragma unroll
                    for (int Mt = 0; Mt < 2; ++Mt) {
                        oacc[Mt] = __builtin_amdgcn_mfma_f32_32x32x16_f16(A[Mt], bo0.h, oacc[Mt], 0, 0, 0);
                        oacc[Mt] = __builtin_amdgcn_mfma_f32_32x32x16_f16(A[Mt], bo1.h, oacc[Mt], 0, 0, 0);
                    }
                }
            }
            __syncthreads();                 // both kq halves done with slots
            if (j < 11) { pair_store(); __syncthreads(); }
        }

        // ---- phase A: partner partial exchange for main acc (stage region, 32 KB) ----
        float* Xm = (float*)smem;
        {
            const int slot = (nj * 2 + mi) * 2 + (1 - kq);
#pragma unroll
            for (int r = 0; r < 16; ++r)
                Xm[(slot * 16 + r) * 64 + lane] = frn_add(acc_h[1 - kq][r], acc_l[1 - kq][r]);
        }
        __syncthreads();

        // ---- owned hidden tile: sum partials, state update, spike pack ----
        {
            const int slot = (nj * 2 + mi) * 2 + kq;
            uint32_t zzw = 0;
#pragma unroll
            for (int r = 0; r < 16; ++r) {
                float a = frn_add(frn_add(acc_h[kq][r], acc_l[kq][r]),
                                  Xm[(slot * 16 + r) * 64 + lane]);
                float iold = iS[r];
                float vd = frn_add(vS[r], frn_mul(0.1f, frn_add(frn_sub(0.0f, vS[r]), iold)));
                bool z = frn_sub(vd, 1.0f) > 0.0f;
                vS[r] = z ? 0.0f : vd;
                iS[r] = frn_add(frn_sub(iold, frn_mul(0.2f, iold)), a);
                unsigned long long bal = __ballot(z);
                int ra = (r & 3) + ((r >> 2) << 3);
                if (lane == ra)     zzw = (uint32_t)bal;
                if (lane == ra + 4) zzw = (uint32_t)(bal >> 32);
            }
            if (t < T - 1 && lane < 32) {
                uint32_t* bg = bitsRing + (size_t)(t + 1) * SLOT_U32;
                __hip_atomic_store(&bg[(size_t)(rowBase + mi * 64 + kq * 32 + lane) * 48 + 16 + hb * 2 + nj],
                                   zzw, __ATOMIC_RELAXED, __HIP_MEMORY_SCOPE_AGENT);
            }
        }
        __syncthreads();    // Xm reads done; stage region free for phase B

        // ---- phase B: readout-partial exchange (stage region, 32 KB) ----
        float* Xo = (float*)smem;
        if (ln < 16) {
#pragma unroll
            for (int Mt = 0; Mt < 2; ++Mt)
#pragma unroll
                for (int r = 0; r < 16; ++r) {
                    int rr = (r & 3) + ((r >> 2) << 3) + (q << 2);
                    Xo[((wv * 2 + Mt) * 32 + rr) * 16 + ln] = oacc[Mt][r];
                }
        }
        __syncthreads();

        // ---- o-state update (lagged: this step's oacc = z(t-1)@W = S(t-1)) ----
#pragma unroll
        for (int jj = 0; jj < 4; ++jj) {
            const int R = wv * 16 + rgrp * 4 + jj;
            const int miR = R >> 6, MtR = (R >> 5) & 1, rr = R & 31;
            const int wb0 = miR * 2;
            float s = Xo[(((wb0 + 0) * 2 + MtR) * 32 + rr) * 16 + colo];
            s = frn_add(s, Xo[(((wb0 + 1) * 2 + MtR) * 32 + rr) * 16 + colo]);
            s = frn_add(s, Xo[(((wb0 + 4) * 2 + MtR) * 32 + rr) * 16 + colo]);
            s = frn_add(s, Xo[(((wb0 + 5) * 2 + MtR) * 32 + rr) * 16 + colo]);
            // voltages[t-1] = vo + 0.1*(io(t-2) - vo); then io(t-1) = 0.8*io + S(t-1)
            vo4[jj] = frn_add(vo4[jj], frn_mul(0.1f, frn_sub(io4[jj], vo4[jj])));
            mx4[jj] = fmaxf(mx4[jj], vo4[jj]);
            io4[jj] = frn_add(frn_sub(io4[jj], frn_mul(0.2f, io4[jj])), s);
        }

        if (t < T - 1) {
            enc_step(t + 1);
            pair_load(0);     // next step's pair 0 (overlaps barrier wait)
        }
    }

    // epilogue: voltages[T-1]
#pragma unroll
    for (int jj = 0; jj < 4; ++jj) {
        vo4[jj] = frn_add(vo4[jj], frn_mul(0.1f, frn_sub(io4[jj], vo4[jj])));
        mx4[jj] = fmaxf(mx4[jj], vo4[jj]);
    }
#pragma unroll
    for (int jj = 0; jj < 4; ++jj) {
        const int R = wv * 16 + rgrp * 4 + jj;
        outm[(size_t)(rowBase + R) * 256 + hb * 16 + colo] = mx4[jj];
    }
}

// ---------------------------------------------------------------------------
// softmax over O=256, in-place on d_out
// ---------------------------------------------------------------------------
__global__ void k_sm(float* __restrict__ o)
{
    const int lane = threadIdx.x & 63;
    const int wv4 = threadIdx.x >> 6;
    const int row = blockIdx.x * 8 + wv4 * 2 + (lane >> 5);
    const int ln = lane & 31;
    float* pr = o + (size_t)row * 256;
    float v[8];
#pragma unroll
    for (int i = 0; i < 8; ++i) v[i] = pr[ln + i * 32];
    float m = v[0];
#pragma unroll
    for (int i = 1; i < 8; ++i) m = fmaxf(m, v[i]);
#pragma unroll
    for (int off = 16; off; off >>= 1) m = fmaxf(m, __shfl_xor(m, off, 32));
    float s = 0.f;
#pragma unroll
    for (int i = 0; i < 8; ++i) { v[i] = expf(v[i] - m); s += v[i]; }
#pragma unroll
    for (int off = 16; off; off >>= 1) s += __shfl_xor(s, off, 32);
#pragma unroll
    for (int i = 0; i < 8; ++i) pr[ln + i * 32] = v[i] / s;
}

// ---------------------------------------------------------------------------
extern "C" void kernel_launch(void* const* d_in, const int* in_sizes, int n_in,
                              void* d_out, int out_size, void* d_ws, size_t ws_size,
                              hipStream_t stream)
{
    const float* x     = (const float*)d_in[0];
    const float* w_in  = (const float*)d_in[1];
    const float* w_rec = (const float*)d_in[2];
    const float* w_out = (const float*)d_in[3];
    const int*   seq   = (const int*)d_in[4];
    uint8_t* ws = (uint8_t*)d_ws;
    float* out = (float*)d_out;

    k_prep<<<1024, 256, 0, stream>>>(w_in, w_rec, w_out, ws);

    // 61952 B dynamic LDS — MUST stay under the 64 KiB per-workgroup dispatch
    // limit (requesting more silently rejects the launch -> uniform softmax).
    k_snn<<<256, 512, 61952, stream>>>(x, ws, out, seq);
    k_sm<<<256, 256, 0, stream>>>(out);
}

// Round 6
// 5650.912 us; speedup vs baseline: 1.0009x; 1.0009x over previous
//
#include <hip/hip_runtime.h>
#include <stdint.h>
#include <stddef.h>

// ---------------------------------------------------------------------------
// SNN policy forward, MI355X. B=2048, F=256, H=1024, O=256, T=64.
// 256 blocks x 512 threads (8 waves = 2/SIMD, 1 block/CU). Block = 128 rows x 64 h.
// Wave (nj,mi,kq): tile 64m(2Mt) x 32n(nj), K-chunks of parity kq (12 of 24).
// Partner waves (kq=0/1) sum main-GEMM partials via LDS (phase A); readout
// partials exchanged in phase B (same 36KB stage region).
// v_mfma_f32_32x32x16_f16, A = spikes {0,1} exact, B = f32 weights hi+lo f16.
// NOTE: __launch_bounds__(512,1): the 2nd arg acts as workgroups/CU here;
// (512,2) capped VGPRs at 128 -> ~70 regs spilled -> 6.9 GB scratch traffic.
// ---------------------------------------------------------------------------

typedef _Float16 v8h  __attribute__((ext_vector_type(8)));
typedef float    v16f __attribute__((ext_vector_type(16)));

// workspace layout (bytes)
#define OFF_WSTM  0ull                 // main W tiles [hb16][c24][p2][64][72] f16 = 7,077,888
#define OFF_WSTO  7077888ull           // w_out tiles  [hb16][c16][p2][32][64] f16 = 2,097,152
#define OFF_BITS  9175040ull           // u32 ring [64][2048][48] = 25,165,824
#define OFF_CTR   34340864ull          // u32 [16][64] group barrier counters

#define SLOT_U32  (2048*48)

__device__ __forceinline__ float frn_add(float a, float b){ return __fadd_rn(a,b); }
__device__ __forceinline__ float frn_sub(float a, float b){ return __fsub_rn(a,b); }
__device__ __forceinline__ float frn_mul(float a, float b){ return __fmul_rn(a,b); }

// ---------------------------------------------------------------------------
// prep: tile/convert weights to hi/lo f16, zero bits slot 0 + counters
// ---------------------------------------------------------------------------
__global__ void k_prep(const float* __restrict__ w_in, const float* __restrict__ w_rec,
                       const float* __restrict__ w_out, uint8_t* __restrict__ ws)
{
    const long long stride = (long long)gridDim.x * blockDim.x;
    const long long id = (long long)blockIdx.x * blockDim.x + threadIdx.x;

    _Float16* wm = (_Float16*)(ws + OFF_WSTM);
    for (long long i = id; i < 16LL*24*2*64*72; i += stride) {
        int kk = (int)(i % 72); long long t2 = i / 72;
        int hrow = (int)(t2 % 64); t2 /= 64;
        int p = (int)(t2 % 2);  t2 /= 2;
        int c = (int)(t2 % 24); int hb = (int)(t2 / 24);
        _Float16 val = (_Float16)0.0f;
        if (kk < 64) {
            int h = hb*64 + hrow; int k = c*64 + kk;
            float wv = (k < 512) ? w_in[(size_t)h*512 + k] : w_rec[(size_t)h*1024 + (k - 512)];
            _Float16 hi = (_Float16)wv;
            val = p ? (_Float16)(wv - (float)hi) : hi;
        }
        wm[i] = val;
    }

    // w_out tiles: [(hb*16+c)*2+p][n32][k64], o = hb*16+n (n<16 real, else 0), h = c*64+k
    _Float16* wo = (_Float16*)(ws + OFF_WSTO);
    for (long long i = id; i < 16LL*16*2*32*64; i += stride) {
        int k = (int)(i % 64); long long t2 = i / 64;
        int n = (int)(t2 % 32); t2 /= 32;
        int p = (int)(t2 % 2); t2 /= 2;
        int c = (int)(t2 % 16); int hb = (int)(t2 / 16);
        _Float16 val = (_Float16)0.0f;
        if (n < 16) {
            float wv = w_out[(size_t)(hb*16 + n)*1024 + c*64 + k];
            _Float16 hi = (_Float16)wv;
            val = p ? (_Float16)(wv - (float)hi) : hi;
        }
        wo[i] = val;
    }

    uint32_t* bz = (uint32_t*)(ws + OFF_BITS);
    for (long long i = id; i < SLOT_U32; i += stride) bz[i] = 0u;   // slot 0: z(-1)=0
    uint32_t* ctr = (uint32_t*)(ws + OFF_CTR);
    for (long long i = id; i < 16*64; i += stride) ctr[i] = 0u;
}

// ---------------------------------------------------------------------------
// main persistent kernel
// ---------------------------------------------------------------------------
__global__ __launch_bounds__(512, 1)
void k_snn(const float* __restrict__ x, uint8_t* __restrict__ ws,
           float* __restrict__ outm, const int* __restrict__ seqp)
{
    extern __shared__ uint8_t smem[];
    // [0, 36864): B stage, 2 slots x [p2][64][72] f16 (slot = chunk parity = kq)
    //             aliased end-of-step by Xm (phase A, 32KB) then Xo (phase B, 32KB)
    // [36864, 61952): bits LDS [128][49] u32 (25088 B)

    const int tid  = threadIdx.x;
    const int lane = tid & 63;
    const int wv   = tid >> 6;        // wave 0..7
    const int kq   = wv & 1;          // K parity (chunks c%2==kq)
    const int mi   = (wv >> 1) & 1;   // M half (64 rows)
    const int nj   = wv >> 2;         // N half (32 h)
    const int q    = lane >> 5;
    const int ln   = lane & 31;

    const int b  = blockIdx.x;
    const int bb = b >> 4;                                 // group / batch tile
    const int hb = ((b & 7) << 1) | ((b >> 3) & 1);        // h-slice, XCD-local pairs
    const int rowBase = bb * 128;

    int T = *seqp; if (T > 64) T = 64; if (T < 1) T = 1;

    // o-state: each wave owns rows [wv*16, wv*16+16) x 16 o-cols; 4 elems/lane
    const int colo = ln & 15, rgrp = lane >> 4;            // rgrp 0..3
    float io4[4], vo4[4], mx4[4];
#pragma unroll
    for (int i = 0; i < 4; ++i) { io4[i] = 0.f; vo4[i] = 0.f; mx4[i] = 0.f; }

    v16f zv;
#pragma unroll
    for (int k = 0; k < 16; ++k) zv[k] = 0.f;
    v16f vS = zv, iS = zv;            // owned hidden tile: rows mi*64+kq*32, cols hb*64+nj*32

    // encoder: thread -> row (tid>>2), 8 features at (tid&3)*8
    const int er  = tid >> 2;
    const int fq  = tid & 3;
    float ve[8], cc[8];
    {
        const float* xr = x + (size_t)(rowBase + er) * 256 + (hb & 7) * 32 + fq * 8;
        const float sgn = (hb < 8) ? 50.0f : -50.0f;
#pragma unroll
        for (int f = 0; f < 8; ++f) {
            cc[f] = fmaxf(frn_mul(sgn, xr[f]), 0.0f);
            ve[f] = 0.0f;
        }
    }

    uint32_t* const bitsRing = (uint32_t*)(ws + OFF_BITS);
    uint32_t* const bitsL = (uint32_t*)(smem + 36864);
    uint32_t* const ctr = (uint32_t*)(ws + OFF_CTR) + bb * 64;
    const uint4* const wstg = (const uint4*)(ws + OFF_WSTM) + (size_t)(hb * 24) * 1152;
    const _Float16* const wouts = (const _Float16*)(ws + OFF_WSTO);
    uint4* const Bs = (uint4*)smem;

    auto enc_step = [&](int dstSlot) {
        uint32_t byte = 0;
#pragma unroll
        for (int f = 0; f < 8; ++f) {
            float vv = ve[f];
            vv = frn_add(vv, frn_mul(0.1f, frn_add(frn_sub(0.0f, vv), cc[f])));
            bool zz = frn_sub(vv, 1.0f) > 0.0f;
            ve[f] = zz ? 0.0f : vv;
            byte |= zz ? (1u << f) : 0u;
        }
        uint32_t w = byte << (fq * 8);
        w |= __shfl_xor(w, 1);
        w |= __shfl_xor(w, 2);
        if (fq == 0)
            __hip_atomic_store(&bitsRing[(size_t)dstSlot * SLOT_U32 + (size_t)(rowBase + er) * 48 + hb],
                               w, __ATOMIC_RELAXED, __HIP_MEMORY_SCOPE_AGENT);
    };

    auto gbar = [&](int phase) {
        asm volatile("s_waitcnt vmcnt(0)" ::: "memory");
        __syncthreads();
        if (tid == 0) {
            __hip_atomic_fetch_add(ctr, 1u, __ATOMIC_RELAXED, __HIP_MEMORY_SCOPE_AGENT);
            const uint32_t tgt = 16u * (uint32_t)(phase + 1);
            while (__hip_atomic_load(ctr, __ATOMIC_RELAXED, __HIP_MEMORY_SCOPE_AGENT) < tgt)
                __builtin_amdgcn_s_sleep(1);
            asm volatile("" ::: "memory");
        }
        __syncthreads();
    };

    enc_step(0);   // xt(0) -> slot 0

    // staging regs: chunk pair = 2304 uint4 over 512 threads
    uint4 pf[5];
    auto pair_load = [&](int pr) {
        const uint4* g = wstg + (size_t)(pr * 2) * 1152;
        pf[0] = g[tid]; pf[1] = g[tid + 512]; pf[2] = g[tid + 1024]; pf[3] = g[tid + 1536];
        if (tid < 256) pf[4] = g[tid + 2048];
    };
    auto pair_store = [&]() {
        Bs[tid] = pf[0]; Bs[tid + 512] = pf[1]; Bs[tid + 1024] = pf[2]; Bs[tid + 1536] = pf[3];
        if (tid < 256) Bs[tid + 2048] = pf[4];
    };
    pair_load(0);

    const _Float16* const Bt = (const _Float16*)(smem + kq * 18432);

    for (int t = 0; t < T; ++t) {
        gbar(t);

        // ---- bits slot t -> LDS [128][49] (12 agent loads/thread) ----
        uint32_t bw[12];
        {
            const uint32_t* bsrc = bitsRing + (size_t)t * SLOT_U32 + (size_t)rowBase * 48;
#pragma unroll
            for (int i2 = 0; i2 < 12; ++i2)
                bw[i2] = __hip_atomic_load(bsrc + tid + i2 * 512,
                                           __ATOMIC_RELAXED, __HIP_MEMORY_SCOPE_AGENT);
        }
        pair_store();    // pair 0 (preloaded before loop / at end of prev step)
#pragma unroll
        for (int i2 = 0; i2 < 12; ++i2) {
            int idx = tid + i2 * 512;
            int r = idx / 48, wq = idx - r * 48;
            bitsL[r * 49 + wq] = bw[i2];
        }
        __syncthreads();

        v16f acc_h[2], acc_l[2], oacc[2];
        acc_h[0] = zv; acc_h[1] = zv; acc_l[0] = zv; acc_l[1] = zv;
        oacc[0] = zv; oacc[1] = zv;

        for (int j = 0; j < 12; ++j) {
            const int c = 2 * j + kq;
            if (j < 11) pair_load(j + 1);

            const bool odut = (c >= 8) && ((c >= 16) == (nj == 1));
            uint4 wof[8];
            if (odut) {
                const _Float16* wob = wouts + ((size_t)(hb * 16 + (c - 8)) * 2) * 2048;
#pragma unroll
                for (int kc = 0; kc < 4; ++kc)
#pragma unroll
                    for (int p = 0; p < 2; ++p)
                        wof[kc * 2 + p] = *(const uint4*)(wob + (size_t)p * 2048 + ln * 64 + kc * 16 + q * 8);
            }

            uint32_t wb[2];
#pragma unroll
            for (int kc = 0; kc < 4; ++kc) {
                if ((kc & 1) == 0) {
#pragma unroll
                    for (int Mt = 0; Mt < 2; ++Mt)
                        wb[Mt] = bitsL[(mi * 64 + Mt * 32 + ln) * 49 + (c * 2 + (kc >> 1))];
                }
                v8h A[2];
#pragma unroll
                for (int Mt = 0; Mt < 2; ++Mt) {
                    const uint32_t wv2 = wb[Mt];
                    const int sh = ((kc & 1) << 4) + (q << 3);
                    union { uint32_t u[4]; v8h h; } ua;
#pragma unroll
                    for (int j2 = 0; j2 < 4; ++j2) {
                        uint32_t pr = (wv2 >> (sh + 2 * j2)) & 3u;
                        uint32_t m = (pr | (pr << 15)) & 0x10001u;
                        ua.u[j2] = m * 0x3C00u;     // {0,1} spikes -> f16 pair
                    }
                    A[Mt] = ua.h;
                }
                const _Float16* brow = Bt + (size_t)(nj * 32 + ln) * 72 + kc * 16 + q * 8;
                v8h Bh = *(const v8h*)brow;
                v8h Bl = *(const v8h*)(brow + 64 * 72);
#pragma unroll
                for (int Mt = 0; Mt < 2; ++Mt) {
                    acc_h[Mt] = __builtin_amdgcn_mfma_f32_32x32x16_f16(A[Mt], Bh, acc_h[Mt], 0, 0, 0);
                    acc_l[Mt] = __builtin_amdgcn_mfma_f32_32x32x16_f16(A[Mt], Bl, acc_l[Mt], 0, 0, 0);
                }
                if (odut) {
                    union { uint4 u; v8h h; } bo0, bo1;
                    bo0.u = wof[kc * 2 + 0]; bo1.u = wof[kc * 2 + 1];
#pragma unroll
                    for (int Mt = 0; Mt < 2; ++Mt) {
                        oacc[Mt] = __builtin_amdgcn_mfma_f32_32x32x16_f16(A[Mt], bo0.h, oacc[Mt], 0, 0, 0);
                        oacc[Mt] = __builtin_amdgcn_mfma_f32_32x32x16_f16(A[Mt], bo1.h, oacc[Mt], 0, 0, 0);
                    }
                }
            }
            __syncthreads();                 // both kq halves done with slots
            if (j < 11) { pair_store(); __syncthreads(); }
        }

        // ---- phase A: partner partial exchange for main acc (stage region, 32 KB) ----
        float* Xm = (float*)smem;
        {
            const int slot = (nj * 2 + mi) * 2 + (1 - kq);
#pragma unroll
            for (int r = 0; r < 16; ++r)
                Xm[(slot * 16 + r) * 64 + lane] = frn_add(acc_h[1 - kq][r], acc_l[1 - kq][r]);
        }
        __syncthreads();

        // ---- owned hidden tile: sum partials, state update, spike pack ----
        {
            const int slot = (nj * 2 + mi) * 2 + kq;
            uint32_t zzw = 0;
#pragma unroll
            for (int r = 0; r < 16; ++r) {
                float a = frn_add(frn_add(acc_h[kq][r], acc_l[kq][r]),
                                  Xm[(slot * 16 + r) * 64 + lane]);
                float iold = iS[r];
                float vd = frn_add(vS[r], frn_mul(0.1f, frn_add(frn_sub(0.0f, vS[r]), iold)));
                bool z = frn_sub(vd, 1.0f) > 0.0f;
                vS[r] = z ? 0.0f : vd;
                iS[r] = frn_add(frn_sub(iold, frn_mul(0.2f, iold)), a);
                unsigned long long bal = __ballot(z);
                int ra = (r & 3) + ((r >> 2) << 3);
                if (lane == ra)     zzw = (uint32_t)bal;
                if (lane == ra + 4) zzw = (uint32_t)(bal >> 32);
            }
            if (t < T - 1 && lane < 32) {
                uint32_t* bg = bitsRing + (size_t)(t + 1) * SLOT_U32;
                __hip_atomic_store(&bg[(size_t)(rowBase + mi * 64 + kq * 32 + lane) * 48 + 16 + hb * 2 + nj],
                                   zzw, __ATOMIC_RELAXED, __HIP_MEMORY_SCOPE_AGENT);
            }
        }
        __syncthreads();    // Xm reads done; stage region free for phase B

        // ---- phase B: readout-partial exchange (stage region, 32 KB) ----
        float* Xo = (float*)smem;
        if (ln < 16) {
#pragma unroll
            for (int Mt = 0; Mt < 2; ++Mt)
#pragma unroll
                for (int r = 0; r < 16; ++r) {
                    int rr = (r & 3) + ((r >> 2) << 3) + (q << 2);
                    Xo[((wv * 2 + Mt) * 32 + rr) * 16 + ln] = oacc[Mt][r];
                }
        }
        __syncthreads();

        // ---- o-state update (lagged: this step's oacc = z(t-1)@W = S(t-1)) ----
#pragma unroll
        for (int jj = 0; jj < 4; ++jj) {
            const int R = wv * 16 + rgrp * 4 + jj;
            const int miR = R >> 6, MtR = (R >> 5) & 1, rr = R & 31;
            const int wb0 = miR * 2;
            float s = Xo[(((wb0 + 0) * 2 + MtR) * 32 + rr) * 16 + colo];
            s = frn_add(s, Xo[(((wb0 + 1) * 2 + MtR) * 32 + rr) * 16 + colo]);
            s = frn_add(s, Xo[(((wb0 + 4) * 2 + MtR) * 32 + rr) * 16 + colo]);
            s = frn_add(s, Xo[(((wb0 + 5) * 2 + MtR) * 32 + rr) * 16 + colo]);
            // voltages[t-1] = vo + 0.1*(io(t-2) - vo); then io(t-1) = 0.8*io + S(t-1)
            vo4[jj] = frn_add(vo4[jj], frn_mul(0.1f, frn_sub(io4[jj], vo4[jj])));
            mx4[jj] = fmaxf(mx4[jj], vo4[jj]);
            io4[jj] = frn_add(frn_sub(io4[jj], frn_mul(0.2f, io4[jj])), s);
        }

        if (t < T - 1) {
            enc_step(t + 1);
            pair_load(0);     // next step's pair 0 (overlaps barrier wait)
        }
    }

    // epilogue: voltages[T-1]
#pragma unroll
    for (int jj = 0; jj < 4; ++jj) {
        vo4[jj] = frn_add(vo4[jj], frn_mul(0.1f, frn_sub(io4[jj], vo4[jj])));
        mx4[jj] = fmaxf(mx4[jj], vo4[jj]);
    }
#pragma unroll
    for (int jj = 0; jj < 4; ++jj) {
        const int R = wv * 16 + rgrp * 4 + jj;
        outm[(size_t)(rowBase + R) * 256 + hb * 16 + colo] = mx4[jj];
    }
}

// ---------------------------------------------------------------------------
// softmax over O=256, in-place on d_out
// ---------------------------------------------------------------------------
__global__ void k_sm(float* __restrict__ o)
{
    const int lane = threadIdx.x & 63;
    const int wv4 = threadIdx.x >> 6;
    const int row = blockIdx.x * 8 + wv4 * 2 + (lane >> 5);
    const int ln = lane & 31;
    float* pr = o + (size_t)row * 256;
    float v[8];
#pragma unroll
    for (int i = 0; i < 8; ++i) v[i] = pr[ln + i * 32];
    float m = v[0];
#pragma unroll
    for (int i = 1; i < 8; ++i) m = fmaxf(m, v[i]);
#pragma unroll
    for (int off = 16; off; off >>= 1) m = fmaxf(m, __shfl_xor(m, off, 32));
    float s = 0.f;
#pragma unroll
    for (int i = 0; i < 8; ++i) { v[i] = expf(v[i] - m); s += v[i]; }
#pragma unroll
    for (int off = 16; off; off >>= 1) s += __shfl_xor(s, off, 32);
#pragma unroll
    for (int i = 0; i < 8; ++i) pr[ln + i * 32] = v[i] / s;
}

// ---------------------------------------------------------------------------
extern "C" void kernel_launch(void* const* d_in, const int* in_sizes, int n_in,
                              void* d_out, int out_size, void* d_ws, size_t ws_size,
                              hipStream_t stream)
{
    const float* x     = (const float*)d_in[0];
    const float* w_in  = (const float*)d_in[1];
    const float* w_rec = (const float*)d_in[2];
    const float* w_out = (const float*)d_in[3];
    const int*   seq   = (const int*)d_in[4];
    uint8_t* ws = (uint8_t*)d_ws;
    float* out = (float*)d_out;

    k_prep<<<1024, 256, 0, stream>>>(w_in, w_rec, w_out, ws);

    // 61952 B dynamic LDS — MUST stay under the 64 KiB per-workgroup dispatch
    // limit (requesting more silently rejects the launch -> uniform softmax).
    k_snn<<<256, 512, 61952, stream>>>(x, ws, out, seq);
    k_sm<<<256, 256, 0, stream>>>(out);
}

// Round 7
// 5648.512 us; speedup vs baseline: 1.0013x; 1.0004x over previous
//
#include <hip/hip_runtime.h>
#include <stdint.h>
#include <stddef.h>

// ---------------------------------------------------------------------------
// SNN policy forward, MI355X. B=2048, F=256, H=1024, O=256, T=64.
// 256 blocks x 512 threads (8 waves = 2/SIMD, 1 block/CU). Block = 128 rows x 64 h.
// Wave (nj,mi,kq): tile 64m(2Mt) x 32n(nj), K-chunks of parity kq (12 of 24).
// Partner waves (kq=0/1) sum main-GEMM partials via LDS (phase A); readout
// partials exchanged in phase B (same 36KB stage region).
// v_mfma_f32_32x32x16_f16, A = spikes {0,1} exact, B = f32 weights hi+lo f16.
// REGISTER BUDGET: dynamic LDS hides the 1-WG/CU limit from the compiler, so
// its occupancy heuristic targets 4 waves/SIMD -> 128 VGPRs -> ~100 spilled
// regs -> 6.9 GB scratch traffic (rounds 5-6). amdgpu_waves_per_eu(2,2) pins
// the target at 2 waves/EU = 256-VGPR budget; ~230 live regs fit, no spills.
// ---------------------------------------------------------------------------

typedef _Float16 v8h  __attribute__((ext_vector_type(8)));
typedef float    v16f __attribute__((ext_vector_type(16)));

// workspace layout (bytes)
#define OFF_WSTM  0ull                 // main W tiles [hb16][c24][p2][64][72] f16 = 7,077,888
#define OFF_WSTO  7077888ull           // w_out tiles  [hb16][c16][p2][32][64] f16 = 2,097,152
#define OFF_BITS  9175040ull           // u32 ring [64][2048][48] = 25,165,824
#define OFF_CTR   34340864ull          // u32 [16][64] group barrier counters

#define SLOT_U32  (2048*48)

__device__ __forceinline__ float frn_add(float a, float b){ return __fadd_rn(a,b); }
__device__ __forceinline__ float frn_sub(float a, float b){ return __fsub_rn(a,b); }
__device__ __forceinline__ float frn_mul(float a, float b){ return __fmul_rn(a,b); }

// ---------------------------------------------------------------------------
// prep: tile/convert weights to hi/lo f16, zero bits slot 0 + counters
// ---------------------------------------------------------------------------
__global__ void k_prep(const float* __restrict__ w_in, const float* __restrict__ w_rec,
                       const float* __restrict__ w_out, uint8_t* __restrict__ ws)
{
    const long long stride = (long long)gridDim.x * blockDim.x;
    const long long id = (long long)blockIdx.x * blockDim.x + threadIdx.x;

    _Float16* wm = (_Float16*)(ws + OFF_WSTM);
    for (long long i = id; i < 16LL*24*2*64*72; i += stride) {
        int kk = (int)(i % 72); long long t2 = i / 72;
        int hrow = (int)(t2 % 64); t2 /= 64;
        int p = (int)(t2 % 2);  t2 /= 2;
        int c = (int)(t2 % 24); int hb = (int)(t2 / 24);
        _Float16 val = (_Float16)0.0f;
        if (kk < 64) {
            int h = hb*64 + hrow; int k = c*64 + kk;
            float wv = (k < 512) ? w_in[(size_t)h*512 + k] : w_rec[(size_t)h*1024 + (k - 512)];
            _Float16 hi = (_Float16)wv;
            val = p ? (_Float16)(wv - (float)hi) : hi;
        }
        wm[i] = val;
    }

    // w_out tiles: [(hb*16+c)*2+p][n32][k64], o = hb*16+n (n<16 real, else 0), h = c*64+k
    _Float16* wo = (_Float16*)(ws + OFF_WSTO);
    for (long long i = id; i < 16LL*16*2*32*64; i += stride) {
        int k = (int)(i % 64); long long t2 = i / 64;
        int n = (int)(t2 % 32); t2 /= 32;
        int p = (int)(t2 % 2); t2 /= 2;
        int c = (int)(t2 % 16); int hb = (int)(t2 / 16);
        _Float16 val = (_Float16)0.0f;
        if (n < 16) {
            float wv = w_out[(size_t)(hb*16 + n)*1024 + c*64 + k];
            _Float16 hi = (_Float16)wv;
            val = p ? (_Float16)(wv - (float)hi) : hi;
        }
        wo[i] = val;
    }

    uint32_t* bz = (uint32_t*)(ws + OFF_BITS);
    for (long long i = id; i < SLOT_U32; i += stride) bz[i] = 0u;   // slot 0: z(-1)=0
    uint32_t* ctr = (uint32_t*)(ws + OFF_CTR);
    for (long long i = id; i < 16*64; i += stride) ctr[i] = 0u;
}

// ---------------------------------------------------------------------------
// main persistent kernel
// ---------------------------------------------------------------------------
__global__ __attribute__((amdgpu_flat_work_group_size(512, 512), amdgpu_waves_per_eu(2, 2)))
void k_snn(const float* __restrict__ x, uint8_t* __restrict__ ws,
           float* __restrict__ outm, const int* __restrict__ seqp)
{
    extern __shared__ uint8_t smem[];
    // [0, 36864): B stage, 2 slots x [p2][64][72] f16 (slot = chunk parity = kq)
    //             aliased end-of-step by Xm (phase A, 32KB) then Xo (phase B, 32KB)
    // [36864, 61952): bits LDS [128][49] u32 (25088 B)

    const int tid  = threadIdx.x;
    const int lane = tid & 63;
    const int wv   = tid >> 6;        // wave 0..7
    const int kq   = wv & 1;          // K parity (chunks c%2==kq)
    const int mi   = (wv >> 1) & 1;   // M half (64 rows)
    const int nj   = wv >> 2;         // N half (32 h)
    const int q    = lane >> 5;
    const int ln   = lane & 31;

    const int b  = blockIdx.x;
    const int bb = b >> 4;                                 // group / batch tile
    const int hb = ((b & 7) << 1) | ((b >> 3) & 1);        // h-slice, XCD-local pairs
    const int rowBase = bb * 128;

    int T = *seqp; if (T > 64) T = 64; if (T < 1) T = 1;

    // o-state: each wave owns rows [wv*16, wv*16+16) x 16 o-cols; 4 elems/lane
    const int colo = ln & 15, rgrp = lane >> 4;            // rgrp 0..3
    float io4[4], vo4[4], mx4[4];
#pragma unroll
    for (int i = 0; i < 4; ++i) { io4[i] = 0.f; vo4[i] = 0.f; mx4[i] = 0.f; }

    v16f zv;
#pragma unroll
    for (int k = 0; k < 16; ++k) zv[k] = 0.f;
    v16f vS = zv, iS = zv;            // owned hidden tile: rows mi*64+kq*32, cols hb*64+nj*32

    // encoder: thread -> row (tid>>2), 8 features at (tid&3)*8
    const int er  = tid >> 2;
    const int fq  = tid & 3;
    float ve[8], cc[8];
    {
        const float* xr = x + (size_t)(rowBase + er) * 256 + (hb & 7) * 32 + fq * 8;
        const float sgn = (hb < 8) ? 50.0f : -50.0f;
#pragma unroll
        for (int f = 0; f < 8; ++f) {
            cc[f] = fmaxf(frn_mul(sgn, xr[f]), 0.0f);
            ve[f] = 0.0f;
        }
    }

    uint32_t* const bitsRing = (uint32_t*)(ws + OFF_BITS);
    uint32_t* const bitsL = (uint32_t*)(smem + 36864);
    uint32_t* const ctr = (uint32_t*)(ws + OFF_CTR) + bb * 64;
    const uint4* const wstg = (const uint4*)(ws + OFF_WSTM) + (size_t)(hb * 24) * 1152;
    const _Float16* const wouts = (const _Float16*)(ws + OFF_WSTO);
    uint4* const Bs = (uint4*)smem;

    auto enc_step = [&](int dstSlot) {
        uint32_t byte = 0;
#pragma unroll
        for (int f = 0; f < 8; ++f) {
            float vv = ve[f];
            vv = frn_add(vv, frn_mul(0.1f, frn_add(frn_sub(0.0f, vv), cc[f])));
            bool zz = frn_sub(vv, 1.0f) > 0.0f;
            ve[f] = zz ? 0.0f : vv;
            byte |= zz ? (1u << f) : 0u;
        }
        uint32_t w = byte << (fq * 8);
        w |= __shfl_xor(w, 1);
        w |= __shfl_xor(w, 2);
        if (fq == 0)
            __hip_atomic_store(&bitsRing[(size_t)dstSlot * SLOT_U32 + (size_t)(rowBase + er) * 48 + hb],
                               w, __ATOMIC_RELAXED, __HIP_MEMORY_SCOPE_AGENT);
    };

    auto gbar = [&](int phase) {
        asm volatile("s_waitcnt vmcnt(0)" ::: "memory");
        __syncthreads();
        if (tid == 0) {
            __hip_atomic_fetch_add(ctr, 1u, __ATOMIC_RELAXED, __HIP_MEMORY_SCOPE_AGENT);
            const uint32_t tgt = 16u * (uint32_t)(phase + 1);
            while (__hip_atomic_load(ctr, __ATOMIC_RELAXED, __HIP_MEMORY_SCOPE_AGENT) < tgt)
                __builtin_amdgcn_s_sleep(1);
            asm volatile("" ::: "memory");
        }
        __syncthreads();
    };

    enc_step(0);   // xt(0) -> slot 0

    // staging regs: chunk pair = 2304 uint4 over 512 threads
    uint4 pf[5];
    auto pair_load = [&](int pr) {
        const uint4* g = wstg + (size_t)(pr * 2) * 1152;
        pf[0] = g[tid]; pf[1] = g[tid + 512]; pf[2] = g[tid + 1024]; pf[3] = g[tid + 1536];
        if (tid < 256) pf[4] = g[tid + 2048];
    };
    auto pair_store = [&]() {
        Bs[tid] = pf[0]; Bs[tid + 512] = pf[1]; Bs[tid + 1024] = pf[2]; Bs[tid + 1536] = pf[3];
        if (tid < 256) Bs[tid + 2048] = pf[4];
    };
    pair_load(0);

    const _Float16* const Bt = (const _Float16*)(smem + kq * 18432);

    for (int t = 0; t < T; ++t) {
        gbar(t);

        // ---- bits slot t -> LDS [128][49] (12 agent loads/thread) ----
        uint32_t bw[12];
        {
            const uint32_t* bsrc = bitsRing + (size_t)t * SLOT_U32 + (size_t)rowBase * 48;
#pragma unroll
            for (int i2 = 0; i2 < 12; ++i2)
                bw[i2] = __hip_atomic_load(bsrc + tid + i2 * 512,
                                           __ATOMIC_RELAXED, __HIP_MEMORY_SCOPE_AGENT);
        }
        pair_store();    // pair 0 (preloaded before loop / at end of prev step)
#pragma unroll
        for (int i2 = 0; i2 < 12; ++i2) {
            int idx = tid + i2 * 512;
            int r = idx / 48, wq = idx - r * 48;
            bitsL[r * 49 + wq] = bw[i2];
        }
        __syncthreads();

        v16f acc_h[2], acc_l[2], oacc[2];
        acc_h[0] = zv; acc_h[1] = zv; acc_l[0] = zv; acc_l[1] = zv;
        oacc[0] = zv; oacc[1] = zv;

        for (int j = 0; j < 12; ++j) {
            const int c = 2 * j + kq;
            if (j < 11) pair_load(j + 1);

            const bool odut = (c >= 8) && ((c >= 16) == (nj == 1));
            uint4 wof[8];
            if (odut) {
                const _Float16* wob = wouts + ((size_t)(hb * 16 + (c - 8)) * 2) * 2048;
#pragma unroll
                for (int kc = 0; kc < 4; ++kc)
#pragma unroll
                    for (int p = 0; p < 2; ++p)
                        wof[kc * 2 + p] = *(const uint4*)(wob + (size_t)p * 2048 + ln * 64 + kc * 16 + q * 8);
            }

            uint32_t wb[2];
#pragma unroll
            for (int kc = 0; kc < 4; ++kc) {
                if ((kc & 1) == 0) {
#pragma unroll
                    for (int Mt = 0; Mt < 2; ++Mt)
                        wb[Mt] = bitsL[(mi * 64 + Mt * 32 + ln) * 49 + (c * 2 + (kc >> 1))];
                }
                v8h A[2];
#pragma unroll
                for (int Mt = 0; Mt < 2; ++Mt) {
                    const uint32_t wv2 = wb[Mt];
                    const int sh = ((kc & 1) << 4) + (q << 3);
                    union { uint32_t u[4]; v8h h; } ua;
#pragma unroll
                    for (int j2 = 0; j2 < 4; ++j2) {
                        uint32_t pr = (wv2 >> (sh + 2 * j2)) & 3u;
                        uint32_t m = (pr | (pr << 15)) & 0x10001u;
                        ua.u[j2] = m * 0x3C00u;     // {0,1} spikes -> f16 pair
                    }
                    A[Mt] = ua.h;
                }
                const _Float16* brow = Bt + (size_t)(nj * 32 + ln) * 72 + kc * 16 + q * 8;
                v8h Bh = *(const v8h*)brow;
                v8h Bl = *(const v8h*)(brow + 64 * 72);
#pragma unroll
                for (int Mt = 0; Mt < 2; ++Mt) {
                    acc_h[Mt] = __builtin_amdgcn_mfma_f32_32x32x16_f16(A[Mt], Bh, acc_h[Mt], 0, 0, 0);
                    acc_l[Mt] = __builtin_amdgcn_mfma_f32_32x32x16_f16(A[Mt], Bl, acc_l[Mt], 0, 0, 0);
                }
                if (odut) {
                    union { uint4 u; v8h h; } bo0, bo1;
                    bo0.u = wof[kc * 2 + 0]; bo1.u = wof[kc * 2 + 1];
#pragma unroll
                    for (int Mt = 0; Mt < 2; ++Mt) {
                        oacc[Mt] = __builtin_amdgcn_mfma_f32_32x32x16_f16(A[Mt], bo0.h, oacc[Mt], 0, 0, 0);
                        oacc[Mt] = __builtin_amdgcn_mfma_f32_32x32x16_f16(A[Mt], bo1.h, oacc[Mt], 0, 0, 0);
                    }
                }
            }
            __syncthreads();                 // both kq halves done with slots
            if (j < 11) { pair_store(); __syncthreads(); }
        }

        // ---- phase A: partner partial exchange for main acc (stage region, 32 KB) ----
        float* Xm = (float*)smem;
        {
            const int slot = (nj * 2 + mi) * 2 + (1 - kq);
#pragma unroll
            for (int r = 0; r < 16; ++r)
                Xm[(slot * 16 + r) * 64 + lane] = frn_add(acc_h[1 - kq][r], acc_l[1 - kq][r]);
        }
        __syncthreads();

        // ---- owned hidden tile: sum partials, state update, spike pack ----
        {
            const int slot = (nj * 2 + mi) * 2 + kq;
            uint32_t zzw = 0;
#pragma unroll
            for (int r = 0; r < 16; ++r) {
                float a = frn_add(frn_add(acc_h[kq][r], acc_l[kq][r]),
                                  Xm[(slot * 16 + r) * 64 + lane]);
                float iold = iS[r];
                float vd = frn_add(vS[r], frn_mul(0.1f, frn_add(frn_sub(0.0f, vS[r]), iold)));
                bool z = frn_sub(vd, 1.0f) > 0.0f;
                vS[r] = z ? 0.0f : vd;
                iS[r] = frn_add(frn_sub(iold, frn_mul(0.2f, iold)), a);
                unsigned long long bal = __ballot(z);
                int ra = (r & 3) + ((r >> 2) << 3);
                if (lane == ra)     zzw = (uint32_t)bal;
                if (lane == ra + 4) zzw = (uint32_t)(bal >> 32);
            }
            if (t < T - 1 && lane < 32) {
                uint32_t* bg = bitsRing + (size_t)(t + 1) * SLOT_U32;
                __hip_atomic_store(&bg[(size_t)(rowBase + mi * 64 + kq * 32 + lane) * 48 + 16 + hb * 2 + nj],
                                   zzw, __ATOMIC_RELAXED, __HIP_MEMORY_SCOPE_AGENT);
            }
        }
        __syncthreads();    // Xm reads done; stage region free for phase B

        // ---- phase B: readout-partial exchange (stage region, 32 KB) ----
        float* Xo = (float*)smem;
        if (ln < 16) {
#pragma unroll
            for (int Mt = 0; Mt < 2; ++Mt)
#pragma unroll
                for (int r = 0; r < 16; ++r) {
                    int rr = (r & 3) + ((r >> 2) << 3) + (q << 2);
                    Xo[((wv * 2 + Mt) * 32 + rr) * 16 + ln] = oacc[Mt][r];
                }
        }
        __syncthreads();

        // ---- o-state update (lagged: this step's oacc = z(t-1)@W = S(t-1)) ----
#pragma unroll
        for (int jj = 0; jj < 4; ++jj) {
            const int R = wv * 16 + rgrp * 4 + jj;
            const int miR = R >> 6, MtR = (R >> 5) & 1, rr = R & 31;
            const int wb0 = miR * 2;
            float s = Xo[(((wb0 + 0) * 2 + MtR) * 32 + rr) * 16 + colo];
            s = frn_add(s, Xo[(((wb0 + 1) * 2 + MtR) * 32 + rr) * 16 + colo]);
            s = frn_add(s, Xo[(((wb0 + 4) * 2 + MtR) * 32 + rr) * 16 + colo]);
            s = frn_add(s, Xo[(((wb0 + 5) * 2 + MtR) * 32 + rr) * 16 + colo]);
            // voltages[t-1] = vo + 0.1*(io(t-2) - vo); then io(t-1) = 0.8*io + S(t-1)
            vo4[jj] = frn_add(vo4[jj], frn_mul(0.1f, frn_sub(io4[jj], vo4[jj])));
            mx4[jj] = fmaxf(mx4[jj], vo4[jj]);
            io4[jj] = frn_add(frn_sub(io4[jj], frn_mul(0.2f, io4[jj])), s);
        }

        if (t < T - 1) {
            enc_step(t + 1);
            pair_load(0);     // next step's pair 0 (overlaps barrier wait)
        }
    }

    // epilogue: voltages[T-1]
#pragma unroll
    for (int jj = 0; jj < 4; ++jj) {
        vo4[jj] = frn_add(vo4[jj], frn_mul(0.1f, frn_sub(io4[jj], vo4[jj])));
        mx4[jj] = fmaxf(mx4[jj], vo4[jj]);
    }
#pragma unroll
    for (int jj = 0; jj < 4; ++jj) {
        const int R = wv * 16 + rgrp * 4 + jj;
        outm[(size_t)(rowBase + R) * 256 + hb * 16 + colo] = mx4[jj];
    }
}

// ---------------------------------------------------------------------------
// softmax over O=256, in-place on d_out
// ---------------------------------------------------------------------------
__global__ void k_sm(float* __restrict__ o)
{
    const int lane = threadIdx.x & 63;
    const int wv4 = threadIdx.x >> 6;
    const int row = blockIdx.x * 8 + wv4 * 2 + (lane >> 5);
    const int ln = lane & 31;
    float* pr = o + (size_t)row * 256;
    float v[8];
#pragma unroll
    for (int i = 0; i < 8; ++i) v[i] = pr[ln + i * 32];
    float m = v[0];
#pragma unroll
    for (int i = 1; i < 8; ++i) m = fmaxf(m, v[i]);
#pragma unroll
    for (int off = 16; off; off >>= 1) m = fmaxf(m, __shfl_xor(m, off, 32));
    float s = 0.f;
#pragma unroll
    for (int i = 0; i < 8; ++i) { v[i] = expf(v[i] - m); s += v[i]; }
#pragma unroll
    for (int off = 16; off; off >>= 1) s += __shfl_xor(s, off, 32);
#pragma unroll
    for (int i = 0; i < 8; ++i) pr[ln + i * 32] = v[i] / s;
}

// ---------------------------------------------------------------------------
extern "C" void kernel_launch(void* const* d_in, const int* in_sizes, int n_in,
                              void* d_out, int out_size, void* d_ws, size_t ws_size,
                              hipStream_t stream)
{
    const float* x     = (const float*)d_in[0];
    const float* w_in  = (const float*)d_in[1];
    const float* w_rec = (const float*)d_in[2];
    const float* w_out = (const float*)d_in[3];
    const int*   seq   = (const int*)d_in[4];
    uint8_t* ws = (uint8_t*)d_ws;
    float* out = (float*)d_out;

    k_prep<<<1024, 256, 0, stream>>>(w_in, w_rec, w_out, ws);

    // 61952 B dynamic LDS — MUST stay under the 64 KiB per-workgroup dispatch
    // limit (requesting more silently rejects the launch -> uniform softmax).
    k_snn<<<256, 512, 61952, stream>>>(x, ws, out, seq);
    k_sm<<<256, 256, 0, stream>>>(out);
}